// Round 3
// baseline (7209.650 us; speedup 1.0000x reference)
//
#include <hip/hip_runtime.h>

// ---------------------------------------------------------------------------
// MultiLayerNormGRU on MI355X (gfx950) — round 3.
// Phase structure as round 2 (x-precompute + weight-resident recurrence), but
// the recurrent kernel is rebuilt: 16 waves/block, all weights in VGPR,
// DPP-based row reductions, LDS stats broadcast, folded biases.
// ---------------------------------------------------------------------------

#define B_   512
#define T_   512
#define DIN  64
#define H_   256
#define OUT_ 64
#define EPS_ 1e-5f

typedef __attribute__((ext_vector_type(8))) short bf16x8;
typedef __attribute__((ext_vector_type(4))) float f32x4;

__device__ __forceinline__ unsigned short f2bf(float f) {
  unsigned int u = __float_as_uint(f);
  u += 0x7fffu + ((u >> 16) & 1u);          // RNE f32 -> bf16
  return (unsigned short)(u >> 16);
}
__device__ __forceinline__ float bfh(unsigned short u) {
  return __uint_as_float(((unsigned int)u) << 16);
}
__device__ __forceinline__ float sigm_(float x) {
  return __builtin_amdgcn_rcpf(1.f + __expf(-x));
}
__device__ __forceinline__ float tanh_(float x) {
  // 1 - 2/(e^{2x}+1); saturates gracefully via inf/0.
  return 1.f - 2.f * __builtin_amdgcn_rcpf(__expf(2.f * x) + 1.f);
}
template<int C>
__device__ __forceinline__ float dpp_add(float v) {
  int r = __builtin_amdgcn_update_dpp(0, __float_as_int(v), C, 0xF, 0xF, false);
  return v + __int_as_float(r);
}
__device__ __forceinline__ float red16(float v) {  // sum over 16-lane row
  v = dpp_add<0x121>(v);  // row_ror:1
  v = dpp_add<0x122>(v);  // row_ror:2
  v = dpp_add<0x124>(v);  // row_ror:4
  v = dpp_add<0x128>(v);  // row_ror:8
  return v;
}

// ------------------------- prep kernels --------------------------------------
// h-part weights -> MFMA B-fragments (K=256, 8 kc), frag-linear.
__global__ void prep_frag(const float* __restrict__ w, unsigned short* __restrict__ dst,
                          int N, int Ksrc, int koff) {
  int gid = blockIdx.x * 256 + threadIdx.x;
  if (gid >= N * 256) return;
  int n = gid >> 8, k = gid & 255;
  int idx = (((n >> 4) * 8 + (k >> 5)) * 64 + ((n & 15) + 16 * ((k >> 3) & 3))) * 8 + (k & 7);
  dst[idx] = f2bf(w[(size_t)n * Ksrc + koff + k]);
}

// x-part weights row-major [768][KX]: rows 0..511 = Wg[:, :KX], 512..767 = Wc.
__global__ void prep_wx(const float* __restrict__ wg, const float* __restrict__ wc,
                        unsigned short* __restrict__ dst, int KX, int Kg, int Kc) {
  int gid = blockIdx.x * 256 + threadIdx.x;
  if (gid >= 768 * KX) return;
  int n = gid / KX, k = gid - n * KX;
  float v = (n < 512) ? wg[(size_t)n * Kg + k] : wc[(size_t)(n - 512) * Kc + k];
  dst[gid] = f2bf(v);
}

__global__ void bias_cat(const float* __restrict__ bg, const float* __restrict__ bc,
                         float* __restrict__ dst) {
  int i = blockIdx.x * 256 + threadIdx.x;
  if (i < 768) dst[i] = (i < 512) ? bg[i] : bc[i - 512];
}

// ------------------------- precomp GEMM (phases A, C) ------------------------
// P = A @ Wx^T + bias768, bf16 output in transposed layout
// Pc[((bt*TC+tt)*768 + n)*16 + r].
template<int KX, bool AFP32>
__launch_bounds__(256)
__global__ void precomp(const void* __restrict__ Asrc,
                        const unsigned short* __restrict__ wx,
                        const float* __restrict__ bias,
                        unsigned short* __restrict__ Pc,
                        int TC, int t0)
{
  __shared__ __align__(16) unsigned short A_s[8 * 2 * 64 * 8];
  __shared__ __align__(16) unsigned short B_s[8 * 2 * 64 * 8];

  const int tid = threadIdx.x, lane = tid & 63, wv = tid >> 6;
  const int m0 = blockIdx.x * 128, nb = blockIdx.y * 128;
  const int bt = m0 / (TC * 16);
  const int tt0 = (m0 - bt * TC * 16) >> 4;
  const int mq = wv >> 1, nq = wv & 1;
  const int crow0 = (lane >> 4) * 4;

  f32x4 acc[4][4];
#pragma unroll
  for (int i = 0; i < 4; ++i)
#pragma unroll
    for (int j = 0; j < 4; ++j) acc[i][j] = (f32x4){0, 0, 0, 0};

  for (int kb = 0; kb < KX / 64; ++kb) {
    __syncthreads();
#pragma unroll
    for (int it = 0; it < 4; ++it) {
      int s = tid + it * 256;
      int rg = s >> 3, k8 = s & 7;
      int mt = rg >> 4, r15 = rg & 15;
      int dl = r15 + 16 * (k8 & 3), kc = k8 >> 2;
      if (AFP32) {
        const float* xp = (const float*)Asrc +
            (((size_t)(bt * 16 + r15)) * T_ + (t0 + tt0 + mt)) * DIN + kb * 64 + k8 * 8;
        float4 u0 = *(const float4*)xp, u1 = *(const float4*)(xp + 4);
        unsigned short tmp[8];
        tmp[0] = f2bf(u0.x); tmp[1] = f2bf(u0.y); tmp[2] = f2bf(u0.z); tmp[3] = f2bf(u0.w);
        tmp[4] = f2bf(u1.x); tmp[5] = f2bf(u1.y); tmp[6] = f2bf(u1.z); tmp[7] = f2bf(u1.w);
        *reinterpret_cast<bf16x8*>(&A_s[((mt * 2 + kc) * 64 + dl) * 8]) =
            *reinterpret_cast<bf16x8*>(tmp);
      } else {
        const unsigned short* ap = (const unsigned short*)Asrc +
            ((size_t)(m0 + rg)) * KX + kb * 64 + k8 * 8;
        *reinterpret_cast<bf16x8*>(&A_s[((mt * 2 + kc) * 64 + dl) * 8]) =
            *reinterpret_cast<const bf16x8*>(ap);
      }
      const unsigned short* bp = wx + ((size_t)(nb + rg)) * KX + kb * 64 + k8 * 8;
      *reinterpret_cast<bf16x8*>(&B_s[((mt * 2 + kc) * 64 + dl) * 8]) =
          *reinterpret_cast<const bf16x8*>(bp);
    }
    __syncthreads();
#pragma unroll
    for (int kc = 0; kc < 2; ++kc) {
      bf16x8 av[4], bv[4];
#pragma unroll
      for (int i = 0; i < 4; ++i) {
        av[i] = *reinterpret_cast<const bf16x8*>(&A_s[(((mq * 4 + i) * 2 + kc) * 64 + lane) * 8]);
        bv[i] = *reinterpret_cast<const bf16x8*>(&B_s[(((nq * 4 + i) * 2 + kc) * 64 + lane) * 8]);
      }
#pragma unroll
      for (int i = 0; i < 4; ++i)
#pragma unroll
        for (int j = 0; j < 4; ++j)
          acc[i][j] = __builtin_amdgcn_mfma_f32_16x16x32_bf16(av[i], bv[j], acc[i][j], 0, 0, 0);
    }
  }
  float bb[4];
#pragma unroll
  for (int j = 0; j < 4; ++j) bb[j] = bias[nb + nq * 64 + j * 16 + (lane & 15)];
#pragma unroll
  for (int i = 0; i < 4; ++i) {
    int tt = tt0 + mq * 4 + i;
#pragma unroll
    for (int j = 0; j < 4; ++j) {
      int n = nb + nq * 64 + j * 16 + (lane & 15);
      ushort4 o;
      o.x = f2bf(acc[i][j][0] + bb[j]); o.y = f2bf(acc[i][j][1] + bb[j]);
      o.z = f2bf(acc[i][j][2] + bb[j]); o.w = f2bf(acc[i][j][3] + bb[j]);
      *reinterpret_cast<ushort4*>(&Pc[((size_t)(bt * TC + tt) * 768 + n) * 16 + crow0]) = o;
    }
  }
}

// ------------------------- recurrent kernel (phases B, D) --------------------
// 16 waves; wave w owns gate cols [16w,16w+16) (r), [256+16w,..) (z) and cand
// cols [16w,16w+16). All weights in VGPR (3 ntiles x 8 kc x 4 VGPR = 96).
template<bool FIRST, bool L0>
__launch_bounds__(1024, 1)
__global__ void gru_layer(
    const unsigned short* __restrict__ gfrag,
    const unsigned short* __restrict__ cfrag,
    const unsigned short* __restrict__ Pc,
    const float* __restrict__ gnw, const float* __restrict__ gnb,
    const float* __restrict__ cnw, const float* __restrict__ cnb,
    float* __restrict__ hstate,
    unsigned short* __restrict__ h0out,
    int TC)
{
  __shared__ __align__(16) unsigned short h_s[16][264];
  __shared__ __align__(16) unsigned short rh_s[16][264];
  __shared__ __align__(16) float sumP[16][20];
  __shared__ __align__(16) float sqP[16][20];
  __shared__ __align__(8) float2 mnrs[16];

  const int tid = threadIdx.x, lane = tid & 63, wv = tid >> 6;  // wv 0..15
  const int bt = blockIdx.x, b0 = bt * 16;
  const int arow = lane & 15, koff = (lane >> 4) * 8, crow0 = (lane >> 4) * 4;
  const int j = 16 * wv + (lane & 15);      // owned hidden column

  // weights -> VGPR
  bf16x8 wgr[8], wgz[8], wcr[8];
#pragma unroll
  for (int kc = 0; kc < 8; ++kc) {
    wgr[kc] = *reinterpret_cast<const bf16x8*>(&gfrag[((wv * 8 + kc) * 64 + lane) * 8]);
    wgz[kc] = *reinterpret_cast<const bf16x8*>(&gfrag[(((16 + wv) * 8 + kc) * 64 + lane) * 8]);
    wcr[kc] = *reinterpret_cast<const bf16x8*>(&cfrag[((wv * 8 + kc) * 64 + lane) * 8]);
  }
  const float gw_r = gnw[j], gb_r = gnb[j];
  const float gw_z = gnw[256 + j], gb_z = gnb[256 + j];
  const float cw = cnw[j], cb = cnb[j];

  float hm[4];
  if (FIRST) {
#pragma unroll
    for (int g = 0; g < 4; ++g) hm[g] = 0.f;
    for (int i = tid; i < 16 * 264; i += 1024) (&h_s[0][0])[i] = 0;
  } else {
#pragma unroll
    for (int g = 0; g < 4; ++g)
      hm[g] = hstate[(size_t)(b0 + crow0 + g) * 256 + j];
    int r = tid >> 6, c4 = (tid & 63) * 4;
    float4 v = *reinterpret_cast<const float4*>(&hstate[(size_t)(b0 + r) * 256 + c4]);
    ushort4 o;
    o.x = f2bf(v.x); o.y = f2bf(v.y); o.z = f2bf(v.z); o.w = f2bf(v.w);
    *reinterpret_cast<ushort4*>(&h_s[r][c4]) = o;
  }
  __syncthreads();

  const unsigned short* Pr = Pc + ((size_t)bt * TC * 768 + j) * 16;
  const unsigned short* Pz = Pr + 256 * 16;
  const unsigned short* Pn = Pr + 512 * 16;

  for (int tt = 0; tt < TC; ++tt) {
    ushort4 pr4 = *reinterpret_cast<const ushort4*>(Pr + crow0);
    ushort4 pz4 = *reinterpret_cast<const ushort4*>(Pz + crow0);
    ushort4 pn4 = *reinterpret_cast<const ushort4*>(Pn + crow0);
    Pr += 12288; Pz += 12288; Pn += 12288;

    // ---- gates MFMA ----
    f32x4 ar = {0, 0, 0, 0}, az = {0, 0, 0, 0};
#pragma unroll
    for (int kc = 0; kc < 8; ++kc) {
      bf16x8 av = *reinterpret_cast<const bf16x8*>(&h_s[arow][kc * 32 + koff]);
      ar = __builtin_amdgcn_mfma_f32_16x16x32_bf16(av, wgr[kc], ar, 0, 0, 0);
      az = __builtin_amdgcn_mfma_f32_16x16x32_bf16(av, wgz[kc], az, 0, 0, 0);
    }
    float vr[4], vz[4], s4[4], q4[4];
#pragma unroll
    for (int g = 0; g < 4; ++g) {
      vr[g] = ar[g] + bfh(((const unsigned short*)&pr4)[g]);
      vz[g] = az[g] + bfh(((const unsigned short*)&pz4)[g]);
      s4[g] = red16(vr[g] + vz[g]);
      q4[g] = red16(vr[g] * vr[g] + vz[g] * vz[g]);
    }
    if ((lane & 15) == 0) {
      *reinterpret_cast<f32x4*>(&sumP[wv][crow0]) = (f32x4){s4[0], s4[1], s4[2], s4[3]};
      *reinterpret_cast<f32x4*>(&sqP[wv][crow0])  = (f32x4){q4[0], q4[1], q4[2], q4[3]};
    }
    __syncthreads();                                   // B1

    // ---- gate LN stats + apply ----
    {
      int sg = lane >> 4, rr = lane & 15;
      float S = 0.f, Q = 0.f;
#pragma unroll
      for (int i = 0; i < 4; ++i) { S += sumP[4 * sg + i][rr]; Q += sqP[4 * sg + i][rr]; }
      S += __shfl_xor(S, 16, 64); Q += __shfl_xor(Q, 16, 64);
      S += __shfl_xor(S, 32, 64); Q += __shfl_xor(Q, 32, 64);
      float mn = S * (1.f / 512.f);
      float rs = __builtin_amdgcn_rsqf(Q * (1.f / 512.f) - mn * mn + EPS_);
      if (lane < 16) mnrs[lane] = make_float2(mn, rs);
    }
    float zf[4];
#pragma unroll
    for (int g = 0; g < 4; ++g) {
      float2 mr = mnrs[crow0 + g];
      float rv = sigm_(fmaf((vr[g] - mr.x) * mr.y, gw_r, gb_r));
      zf[g]    = sigm_(fmaf((vz[g] - mr.x) * mr.y, gw_z, gb_z));
      rh_s[crow0 + g][j] = f2bf(rv * hm[g]);
    }
    __syncthreads();                                   // B2

    // ---- cand MFMA ----
    f32x4 cc = {0, 0, 0, 0};
#pragma unroll
    for (int kc = 0; kc < 8; ++kc) {
      bf16x8 av = *reinterpret_cast<const bf16x8*>(&rh_s[arow][kc * 32 + koff]);
      cc = __builtin_amdgcn_mfma_f32_16x16x32_bf16(av, wcr[kc], cc, 0, 0, 0);
    }
    float vc[4];
#pragma unroll
    for (int g = 0; g < 4; ++g) {
      vc[g] = cc[g] + bfh(((const unsigned short*)&pn4)[g]);
      s4[g] = red16(vc[g]);
      q4[g] = red16(vc[g] * vc[g]);
    }
    if ((lane & 15) == 0) {
      *reinterpret_cast<f32x4*>(&sumP[wv][crow0]) = (f32x4){s4[0], s4[1], s4[2], s4[3]};
      *reinterpret_cast<f32x4*>(&sqP[wv][crow0])  = (f32x4){q4[0], q4[1], q4[2], q4[3]};
    }
    __syncthreads();                                   // B3

    // ---- cand LN + tanh + h update ----
    {
      int sg = lane >> 4, rr = lane & 15;
      float S = 0.f, Q = 0.f;
#pragma unroll
      for (int i = 0; i < 4; ++i) { S += sumP[4 * sg + i][rr]; Q += sqP[4 * sg + i][rr]; }
      S += __shfl_xor(S, 16, 64); Q += __shfl_xor(Q, 16, 64);
      S += __shfl_xor(S, 32, 64); Q += __shfl_xor(Q, 32, 64);
      float mn = S * (1.f / 256.f);
      float rs = __builtin_amdgcn_rsqf(Q * (1.f / 256.f) - mn * mn + EPS_);
      if (lane < 16) mnrs[lane] = make_float2(mn, rs);
    }
    unsigned short* hrow = L0 ? (h0out + (size_t)(bt * TC + tt) * 4096) : (unsigned short*)nullptr;
#pragma unroll
    for (int g = 0; g < 4; ++g) {
      float2 mr = mnrs[crow0 + g];
      float nv = tanh_(fmaf((vc[g] - mr.x) * mr.y, cw, cb));
      float h = fmaf(zf[g], nv - hm[g], hm[g]);
      hm[g] = h;
      unsigned short hb = f2bf(h);
      h_s[crow0 + g][j] = hb;
      if (L0) hrow[(size_t)(crow0 + g) * 256 + j] = hb;
    }
    __syncthreads();                                   // B4
  }

#pragma unroll
  for (int g = 0; g < 4; ++g)
    hstate[(size_t)(b0 + crow0 + g) * 256 + j] = hm[g];
}

// ------------------------------- FC head -------------------------------------
__launch_bounds__(256)
__global__ void head_k(const float* __restrict__ h1, const float* __restrict__ fcW,
                       const float* __restrict__ fcb, float* __restrict__ out) {
  __shared__ float hs[16][256];
  const int tid = threadIdx.x, b0 = blockIdx.x * 16;
  for (int i = tid; i < 16 * 64; i += 256) {
    int r = i >> 6, c4 = (i & 63) * 4;
    *reinterpret_cast<float4*>(&hs[r][c4]) =
        *reinterpret_cast<const float4*>(&h1[(size_t)(b0 + r) * 256 + c4]);
  }
  __syncthreads();
  int r = tid >> 4, o = (tid & 15) * 4;
  float a0 = fcb[o], a1 = fcb[o + 1], a2 = fcb[o + 2], a3 = fcb[o + 3];
  for (int k = 0; k < 256; ++k) {
    float h = hs[r][k];
    a0 = fmaf(h, fcW[(size_t)(o + 0) * 256 + k], a0);
    a1 = fmaf(h, fcW[(size_t)(o + 1) * 256 + k], a1);
    a2 = fmaf(h, fcW[(size_t)(o + 2) * 256 + k], a2);
    a3 = fmaf(h, fcW[(size_t)(o + 3) * 256 + k], a3);
  }
  float4 ov = {a0, a1, a2, a3};
  *reinterpret_cast<float4*>(&out[(size_t)(b0 + r) * 64 + o]) = ov;
}

// --------------------------------- host --------------------------------------
extern "C" void kernel_launch(void* const* d_in, const int* in_sizes, int n_in,
                              void* d_out, int out_size, void* d_ws, size_t ws_size,
                              hipStream_t stream) {
  (void)in_sizes; (void)n_in; (void)out_size;
  const float* x    = (const float*)d_in[0];
  const float* Wg0  = (const float*)d_in[1];
  const float* bg0  = (const float*)d_in[2];
  const float* gnw0 = (const float*)d_in[3];
  const float* gnb0 = (const float*)d_in[4];
  const float* Wc0  = (const float*)d_in[5];
  const float* bc0  = (const float*)d_in[6];
  const float* cnw0 = (const float*)d_in[7];
  const float* cnb0 = (const float*)d_in[8];
  const float* Wg1  = (const float*)d_in[9];
  const float* bg1  = (const float*)d_in[10];
  const float* gnw1 = (const float*)d_in[11];
  const float* gnb1 = (const float*)d_in[12];
  const float* Wc1  = (const float*)d_in[13];
  const float* bc1  = (const float*)d_in[14];
  const float* cnw1 = (const float*)d_in[15];
  const float* cnb1 = (const float*)d_in[16];
  const float* fcW  = (const float*)d_in[17];
  const float* fcb  = (const float*)d_in[18];

  // fp32 region first (alignment), then bf16 fragment/chunk region.
  float* hst0 = (float*)d_ws;                 // 512*256
  float* hst1 = hst0 + 131072;                // 512*256
  float* b768_0 = hst1 + 131072;              // 768
  float* b768_1 = b768_0 + 768;               // 768
  unsigned short* g0h = (unsigned short*)(b768_1 + 768);
  unsigned short* c0h = g0h + 131072;
  unsigned short* g1h = c0h + 65536;
  unsigned short* c1h = g1h + 131072;
  unsigned short* wx0 = c1h + 65536;
  unsigned short* wx1 = wx0 + 49152;
  unsigned short* dynbase = wx1 + 196608;

  const size_t fixed_bytes = (size_t)((char*)dynbase - (char*)d_ws);
  int TC = 128;
  while (TC > 8) {
    size_t need = fixed_bytes + (size_t)TC * (262144 + 2 * 786432);
    if (need <= ws_size) break;
    TC >>= 1;
  }
  const int NC = T_ / TC;

  unsigned short* P0c = dynbase;
  unsigned short* P1c = P0c + (size_t)TC * 393216;
  unsigned short* h0c = P1c + (size_t)TC * 393216;

  prep_frag<<<512, 256, 0, stream>>>(Wg0, g0h, 512, 320, 64);
  prep_frag<<<256, 256, 0, stream>>>(Wc0, c0h, 256, 320, 64);
  prep_frag<<<512, 256, 0, stream>>>(Wg1, g1h, 512, 512, 256);
  prep_frag<<<256, 256, 0, stream>>>(Wc1, c1h, 256, 512, 256);
  prep_wx<<<192, 256, 0, stream>>>(Wg0, Wc0, wx0, 64, 320, 320);
  prep_wx<<<768, 256, 0, stream>>>(Wg1, Wc1, wx1, 256, 512, 512);
  bias_cat<<<3, 256, 0, stream>>>(bg0, bc0, b768_0);
  bias_cat<<<3, 256, 0, stream>>>(bg1, bc1, b768_1);

  dim3 pgrid(4 * TC, 6);
  for (int c = 0; c < NC; ++c) {
    precomp<64, true><<<pgrid, 256, 0, stream>>>(x, wx0, b768_0, P0c, TC, c * TC);
    if (c == 0)
      gru_layer<true, true><<<32, 1024, 0, stream>>>(g0h, c0h, P0c,
          gnw0, gnb0, cnw0, cnb0, hst0, h0c, TC);
    else
      gru_layer<false, true><<<32, 1024, 0, stream>>>(g0h, c0h, P0c,
          gnw0, gnb0, cnw0, cnb0, hst0, h0c, TC);
    precomp<256, false><<<pgrid, 256, 0, stream>>>(h0c, wx1, b768_1, P1c, TC, 0);
    if (c == 0)
      gru_layer<true, false><<<32, 1024, 0, stream>>>(g1h, c1h, P1c,
          gnw1, gnb1, cnw1, cnb1, hst1, (unsigned short*)nullptr, TC);
    else
      gru_layer<false, false><<<32, 1024, 0, stream>>>(g1h, c1h, P1c,
          gnw1, gnb1, cnw1, cnb1, hst1, (unsigned short*)nullptr, TC);
  }
  head_k<<<32, 256, 0, stream>>>(hst1, fcW, fcb, (float*)d_out);
}

// Round 4
// 4154.041 us; speedup vs baseline: 1.7356x; 1.7356x over previous
//
#include <hip/hip_runtime.h>

// ---------------------------------------------------------------------------
// MultiLayerNormGRU on MI355X (gfx950) — round 4.
// Same phase structure (x-precompute + recurrence), recurrent kernel back to
// 8 waves with gate weights PINNED in VGPRs (asm "+v" per iteration so the
// compiler cannot rematerialize the loads), cand weights in LDS, DPP row
// reductions + mnrs LDS broadcast for LN stats.
// ---------------------------------------------------------------------------

#define B_   512
#define T_   512
#define DIN  64
#define H_   256
#define OUT_ 64
#define EPS_ 1e-5f

typedef __attribute__((ext_vector_type(8))) short bf16x8;
typedef __attribute__((ext_vector_type(4))) float f32x4;

__device__ __forceinline__ unsigned short f2bf(float f) {
  unsigned int u = __float_as_uint(f);
  u += 0x7fffu + ((u >> 16) & 1u);          // RNE f32 -> bf16
  return (unsigned short)(u >> 16);
}
__device__ __forceinline__ float bfh(unsigned short u) {
  return __uint_as_float(((unsigned int)u) << 16);
}
__device__ __forceinline__ float sigm_(float x) {
  return __builtin_amdgcn_rcpf(1.f + __expf(-x));
}
__device__ __forceinline__ float tanh_(float x) {
  return 1.f - 2.f * __builtin_amdgcn_rcpf(__expf(2.f * x) + 1.f);
}
template<int C>
__device__ __forceinline__ float dpp_add(float v) {
  int r = __builtin_amdgcn_update_dpp(0, __float_as_int(v), C, 0xF, 0xF, false);
  return v + __int_as_float(r);
}
__device__ __forceinline__ float red16(float v) {  // sum over 16-lane row
  v = dpp_add<0x121>(v);
  v = dpp_add<0x122>(v);
  v = dpp_add<0x124>(v);
  v = dpp_add<0x128>(v);
  return v;
}

#define PIN8(a) asm volatile("" : "+v"(a[0]), "+v"(a[1]), "+v"(a[2]), "+v"(a[3]), \
                                  "+v"(a[4]), "+v"(a[5]), "+v"(a[6]), "+v"(a[7]))

// ------------------------- prep kernels --------------------------------------
__global__ void prep_frag(const float* __restrict__ w, unsigned short* __restrict__ dst,
                          int N, int Ksrc, int koff) {
  int gid = blockIdx.x * 256 + threadIdx.x;
  if (gid >= N * 256) return;
  int n = gid >> 8, k = gid & 255;
  int idx = (((n >> 4) * 8 + (k >> 5)) * 64 + ((n & 15) + 16 * ((k >> 3) & 3))) * 8 + (k & 7);
  dst[idx] = f2bf(w[(size_t)n * Ksrc + koff + k]);
}

__global__ void prep_wx(const float* __restrict__ wg, const float* __restrict__ wc,
                        unsigned short* __restrict__ dst, int KX, int Kg, int Kc) {
  int gid = blockIdx.x * 256 + threadIdx.x;
  if (gid >= 768 * KX) return;
  int n = gid / KX, k = gid - n * KX;
  float v = (n < 512) ? wg[(size_t)n * Kg + k] : wc[(size_t)(n - 512) * Kc + k];
  dst[gid] = f2bf(v);
}

__global__ void bias_cat(const float* __restrict__ bg, const float* __restrict__ bc,
                         float* __restrict__ dst) {
  int i = blockIdx.x * 256 + threadIdx.x;
  if (i < 768) dst[i] = (i < 512) ? bg[i] : bc[i - 512];
}

// ------------------------- precomp GEMM (phases A, C) ------------------------
template<int KX, bool AFP32>
__launch_bounds__(256)
__global__ void precomp(const void* __restrict__ Asrc,
                        const unsigned short* __restrict__ wx,
                        const float* __restrict__ bias,
                        unsigned short* __restrict__ Pc,
                        int TC, int t0)
{
  __shared__ __align__(16) unsigned short A_s[8 * 2 * 64 * 8];
  __shared__ __align__(16) unsigned short B_s[8 * 2 * 64 * 8];

  const int tid = threadIdx.x, lane = tid & 63, wv = tid >> 6;
  const int m0 = blockIdx.x * 128, nb = blockIdx.y * 128;
  const int bt = m0 / (TC * 16);
  const int tt0 = (m0 - bt * TC * 16) >> 4;
  const int mq = wv >> 1, nq = wv & 1;
  const int crow0 = (lane >> 4) * 4;

  f32x4 acc[4][4];
#pragma unroll
  for (int i = 0; i < 4; ++i)
#pragma unroll
    for (int j = 0; j < 4; ++j) acc[i][j] = (f32x4){0, 0, 0, 0};

  for (int kb = 0; kb < KX / 64; ++kb) {
    __syncthreads();
#pragma unroll
    for (int it = 0; it < 4; ++it) {
      int s = tid + it * 256;
      int rg = s >> 3, k8 = s & 7;
      int mt = rg >> 4, r15 = rg & 15;
      int dl = r15 + 16 * (k8 & 3), kc = k8 >> 2;
      if (AFP32) {
        const float* xp = (const float*)Asrc +
            (((size_t)(bt * 16 + r15)) * T_ + (t0 + tt0 + mt)) * DIN + kb * 64 + k8 * 8;
        float4 u0 = *(const float4*)xp, u1 = *(const float4*)(xp + 4);
        unsigned short tmp[8];
        tmp[0] = f2bf(u0.x); tmp[1] = f2bf(u0.y); tmp[2] = f2bf(u0.z); tmp[3] = f2bf(u0.w);
        tmp[4] = f2bf(u1.x); tmp[5] = f2bf(u1.y); tmp[6] = f2bf(u1.z); tmp[7] = f2bf(u1.w);
        *reinterpret_cast<bf16x8*>(&A_s[((mt * 2 + kc) * 64 + dl) * 8]) =
            *reinterpret_cast<bf16x8*>(tmp);
      } else {
        const unsigned short* ap = (const unsigned short*)Asrc +
            ((size_t)(m0 + rg)) * KX + kb * 64 + k8 * 8;
        *reinterpret_cast<bf16x8*>(&A_s[((mt * 2 + kc) * 64 + dl) * 8]) =
            *reinterpret_cast<const bf16x8*>(ap);
      }
      const unsigned short* bp = wx + ((size_t)(nb + rg)) * KX + kb * 64 + k8 * 8;
      *reinterpret_cast<bf16x8*>(&B_s[((mt * 2 + kc) * 64 + dl) * 8]) =
          *reinterpret_cast<const bf16x8*>(bp);
    }
    __syncthreads();
#pragma unroll
    for (int kc = 0; kc < 2; ++kc) {
      bf16x8 av[4], bv[4];
#pragma unroll
      for (int i = 0; i < 4; ++i) {
        av[i] = *reinterpret_cast<const bf16x8*>(&A_s[(((mq * 4 + i) * 2 + kc) * 64 + lane) * 8]);
        bv[i] = *reinterpret_cast<const bf16x8*>(&B_s[(((nq * 4 + i) * 2 + kc) * 64 + lane) * 8]);
      }
#pragma unroll
      for (int i = 0; i < 4; ++i)
#pragma unroll
        for (int j = 0; j < 4; ++j)
          acc[i][j] = __builtin_amdgcn_mfma_f32_16x16x32_bf16(av[i], bv[j], acc[i][j], 0, 0, 0);
    }
  }
  float bb[4];
#pragma unroll
  for (int j = 0; j < 4; ++j) bb[j] = bias[nb + nq * 64 + j * 16 + (lane & 15)];
#pragma unroll
  for (int i = 0; i < 4; ++i) {
    int tt = tt0 + mq * 4 + i;
#pragma unroll
    for (int j = 0; j < 4; ++j) {
      int n = nb + nq * 64 + j * 16 + (lane & 15);
      ushort4 o;
      o.x = f2bf(acc[i][j][0] + bb[j]); o.y = f2bf(acc[i][j][1] + bb[j]);
      o.z = f2bf(acc[i][j][2] + bb[j]); o.w = f2bf(acc[i][j][3] + bb[j]);
      *reinterpret_cast<ushort4*>(&Pc[((size_t)(bt * TC + tt) * 768 + n) * 16 + crow0]) = o;
    }
  }
}

// ------------------------- recurrent kernel (phases B, D) --------------------
// 8 waves; wave w owns gate ntiles {2w,2w+1,16+2w,17+2w} (VGPR-pinned) and
// cand ntiles {2w,2w+1} (LDS). Per-thread epilogue: 2 r, 2 z, 2 n over 4 rows.
template<bool FIRST, bool L0>
__launch_bounds__(512, 2)
__global__ void gru_layer(
    const unsigned short* __restrict__ gfrag,
    const unsigned short* __restrict__ cfrag,
    const unsigned short* __restrict__ Pc,
    const float* __restrict__ gnw, const float* __restrict__ gnb,
    const float* __restrict__ cnw, const float* __restrict__ cnb,
    float* __restrict__ hstate,
    unsigned short* __restrict__ h0out,
    int TC)
{
  __shared__ __align__(16) unsigned short wc_s[16 * 8 * 64 * 8];  // 128 KB cand
  __shared__ __align__(16) unsigned short h_s[16][264];
  __shared__ __align__(16) unsigned short rh_s[16][264];
  __shared__ __align__(16) float sumP[8][20];
  __shared__ __align__(16) float sqP[8][20];
  __shared__ __align__(8) float2 mnrs[16];

  const int tid = threadIdx.x, lane = tid & 63, wv = tid >> 6;  // wv 0..7
  const int bt = blockIdx.x, b0 = bt * 16;
  const int arow = lane & 15, koff = (lane >> 4) * 8, crow0 = (lane >> 4) * 4;
  const int colr0 = 32 * wv + (lane & 15), colr1 = colr0 + 16;
  const int nt0 = 2 * wv, nt1 = 2 * wv + 1, nt2 = 16 + 2 * wv, nt3 = 17 + 2 * wv;

  // cand weights -> LDS (one-time)
  for (int i = tid; i < 8192; i += 512)
    *reinterpret_cast<bf16x8*>(&wc_s[i * 8]) = *reinterpret_cast<const bf16x8*>(&cfrag[i * 8]);

  // gate weights -> VGPR (4 ntiles x 8 kc = 128 VGPRs), pinned in the loop
  bf16x8 wgr0[8], wgr1[8], wgr2[8], wgr3[8];
#pragma unroll
  for (int kc = 0; kc < 8; ++kc) {
    wgr0[kc] = *reinterpret_cast<const bf16x8*>(&gfrag[((nt0 * 8 + kc) * 64 + lane) * 8]);
    wgr1[kc] = *reinterpret_cast<const bf16x8*>(&gfrag[((nt1 * 8 + kc) * 64 + lane) * 8]);
    wgr2[kc] = *reinterpret_cast<const bf16x8*>(&gfrag[((nt2 * 8 + kc) * 64 + lane) * 8]);
    wgr3[kc] = *reinterpret_cast<const bf16x8*>(&gfrag[((nt3 * 8 + kc) * 64 + lane) * 8]);
  }

  const float gw_r0 = gnw[colr0], gb_r0 = gnb[colr0];
  const float gw_r1 = gnw[colr1], gb_r1 = gnb[colr1];
  const float gw_z0 = gnw[256 + colr0], gb_z0 = gnb[256 + colr0];
  const float gw_z1 = gnw[256 + colr1], gb_z1 = gnb[256 + colr1];
  const float cw0 = cnw[colr0], cb0 = cnb[colr0];
  const float cw1 = cnw[colr1], cb1 = cnb[colr1];

  float hm[2][4];
  if (FIRST) {
#pragma unroll
    for (int g = 0; g < 4; ++g) { hm[0][g] = 0.f; hm[1][g] = 0.f; }
    for (int i = tid; i < 16 * 264; i += 512) (&h_s[0][0])[i] = 0;
  } else {
#pragma unroll
    for (int g = 0; g < 4; ++g) {
      hm[0][g] = hstate[(size_t)(b0 + crow0 + g) * 256 + colr0];
      hm[1][g] = hstate[(size_t)(b0 + crow0 + g) * 256 + colr1];
    }
    int r = tid >> 5, c8 = (tid & 31) * 8;
    float4 v0 = *reinterpret_cast<const float4*>(&hstate[(size_t)(b0 + r) * 256 + c8]);
    float4 v1 = *reinterpret_cast<const float4*>(&hstate[(size_t)(b0 + r) * 256 + c8 + 4]);
    ushort4 o0, o1;
    o0.x = f2bf(v0.x); o0.y = f2bf(v0.y); o0.z = f2bf(v0.z); o0.w = f2bf(v0.w);
    o1.x = f2bf(v1.x); o1.y = f2bf(v1.y); o1.z = f2bf(v1.z); o1.w = f2bf(v1.w);
    *reinterpret_cast<ushort4*>(&h_s[r][c8]) = o0;
    *reinterpret_cast<ushort4*>(&h_s[r][c8 + 4]) = o1;
  }
  __syncthreads();

  const unsigned short* Pr0 = Pc + ((size_t)bt * TC * 768 + colr0) * 16;

  for (int tt = 0; tt < TC; ++tt) {
    // pin gate weights: compiler must keep them live in VGPRs across the loop
    PIN8(wgr0); PIN8(wgr1); PIN8(wgr2); PIN8(wgr3);

    ushort4 pr0 = *reinterpret_cast<const ushort4*>(Pr0 + crow0);
    ushort4 pr1 = *reinterpret_cast<const ushort4*>(Pr0 + 16 * 16 + crow0);
    ushort4 pz0 = *reinterpret_cast<const ushort4*>(Pr0 + 256 * 16 + crow0);
    ushort4 pz1 = *reinterpret_cast<const ushort4*>(Pr0 + 272 * 16 + crow0);
    ushort4 pn0 = *reinterpret_cast<const ushort4*>(Pr0 + 512 * 16 + crow0);
    ushort4 pn1 = *reinterpret_cast<const ushort4*>(Pr0 + 528 * 16 + crow0);
    Pr0 += 12288;

    // ---- gates MFMA (register weights) ----
    f32x4 a0 = {0, 0, 0, 0}, a1 = {0, 0, 0, 0}, a2 = {0, 0, 0, 0}, a3 = {0, 0, 0, 0};
#pragma unroll
    for (int kc = 0; kc < 8; ++kc) {
      bf16x8 av = *reinterpret_cast<const bf16x8*>(&h_s[arow][kc * 32 + koff]);
      a0 = __builtin_amdgcn_mfma_f32_16x16x32_bf16(av, wgr0[kc], a0, 0, 0, 0);
      a1 = __builtin_amdgcn_mfma_f32_16x16x32_bf16(av, wgr1[kc], a1, 0, 0, 0);
      a2 = __builtin_amdgcn_mfma_f32_16x16x32_bf16(av, wgr2[kc], a2, 0, 0, 0);
      a3 = __builtin_amdgcn_mfma_f32_16x16x32_bf16(av, wgr3[kc], a3, 0, 0, 0);
    }
    float vr0[4], vr1[4], vz0[4], vz1[4];
    {
      float s4[4], q4[4];
#pragma unroll
      for (int g = 0; g < 4; ++g) {
        vr0[g] = a0[g] + bfh(((const unsigned short*)&pr0)[g]);
        vr1[g] = a1[g] + bfh(((const unsigned short*)&pr1)[g]);
        vz0[g] = a2[g] + bfh(((const unsigned short*)&pz0)[g]);
        vz1[g] = a3[g] + bfh(((const unsigned short*)&pz1)[g]);
        s4[g] = red16(vr0[g] + vr1[g] + vz0[g] + vz1[g]);
        q4[g] = red16(vr0[g] * vr0[g] + vr1[g] * vr1[g] + vz0[g] * vz0[g] + vz1[g] * vz1[g]);
      }
      if ((lane & 15) == 0) {
        *reinterpret_cast<f32x4*>(&sumP[wv][crow0]) = (f32x4){s4[0], s4[1], s4[2], s4[3]};
        *reinterpret_cast<f32x4*>(&sqP[wv][crow0])  = (f32x4){q4[0], q4[1], q4[2], q4[3]};
      }
    }
    __syncthreads();                                   // B1

    // ---- gate LN stats + apply ----
    {
      int sg = lane >> 4, rr = lane & 15;
      float S = sumP[2 * sg][rr] + sumP[2 * sg + 1][rr];
      float Q = sqP[2 * sg][rr] + sqP[2 * sg + 1][rr];
      S += __shfl_xor(S, 16, 64); Q += __shfl_xor(Q, 16, 64);
      S += __shfl_xor(S, 32, 64); Q += __shfl_xor(Q, 32, 64);
      float mn = S * (1.f / 512.f);
      float rs = __builtin_amdgcn_rsqf(Q * (1.f / 512.f) - mn * mn + EPS_);
      if (lane < 16) mnrs[lane] = make_float2(mn, rs);
    }
    float zf[2][4];
#pragma unroll
    for (int g = 0; g < 4; ++g) {
      float2 mr = mnrs[crow0 + g];
      float rv0 = sigm_(fmaf((vr0[g] - mr.x) * mr.y, gw_r0, gb_r0));
      float rv1 = sigm_(fmaf((vr1[g] - mr.x) * mr.y, gw_r1, gb_r1));
      zf[0][g]  = sigm_(fmaf((vz0[g] - mr.x) * mr.y, gw_z0, gb_z0));
      zf[1][g]  = sigm_(fmaf((vz1[g] - mr.x) * mr.y, gw_z1, gb_z1));
      rh_s[crow0 + g][colr0] = f2bf(rv0 * hm[0][g]);
      rh_s[crow0 + g][colr1] = f2bf(rv1 * hm[1][g]);
    }
    __syncthreads();                                   // B2

    // ---- cand MFMA (LDS weights) ----
    f32x4 c0 = {0, 0, 0, 0}, c1 = {0, 0, 0, 0};
#pragma unroll
    for (int kc = 0; kc < 8; ++kc) {
      bf16x8 av = *reinterpret_cast<const bf16x8*>(&rh_s[arow][kc * 32 + koff]);
      bf16x8 b0v = *reinterpret_cast<const bf16x8*>(&wc_s[((nt0 * 8 + kc) * 64 + lane) * 8]);
      bf16x8 b1v = *reinterpret_cast<const bf16x8*>(&wc_s[((nt1 * 8 + kc) * 64 + lane) * 8]);
      c0 = __builtin_amdgcn_mfma_f32_16x16x32_bf16(av, b0v, c0, 0, 0, 0);
      c1 = __builtin_amdgcn_mfma_f32_16x16x32_bf16(av, b1v, c1, 0, 0, 0);
    }
    float vc0[4], vc1[4];
    {
      float s4[4], q4[4];
#pragma unroll
      for (int g = 0; g < 4; ++g) {
        vc0[g] = c0[g] + bfh(((const unsigned short*)&pn0)[g]);
        vc1[g] = c1[g] + bfh(((const unsigned short*)&pn1)[g]);
        s4[g] = red16(vc0[g] + vc1[g]);
        q4[g] = red16(vc0[g] * vc0[g] + vc1[g] * vc1[g]);
      }
      if ((lane & 15) == 0) {
        *reinterpret_cast<f32x4*>(&sumP[wv][crow0]) = (f32x4){s4[0], s4[1], s4[2], s4[3]};
        *reinterpret_cast<f32x4*>(&sqP[wv][crow0])  = (f32x4){q4[0], q4[1], q4[2], q4[3]};
      }
    }
    __syncthreads();                                   // B3

    // ---- cand LN + tanh + h update ----
    {
      int sg = lane >> 4, rr = lane & 15;
      float S = sumP[2 * sg][rr] + sumP[2 * sg + 1][rr];
      float Q = sqP[2 * sg][rr] + sqP[2 * sg + 1][rr];
      S += __shfl_xor(S, 16, 64); Q += __shfl_xor(Q, 16, 64);
      S += __shfl_xor(S, 32, 64); Q += __shfl_xor(Q, 32, 64);
      float mn = S * (1.f / 256.f);
      float rs = __builtin_amdgcn_rsqf(Q * (1.f / 256.f) - mn * mn + EPS_);
      if (lane < 16) mnrs[lane] = make_float2(mn, rs);
    }
    unsigned short* hrow = L0 ? (h0out + (size_t)(bt * TC + tt) * 4096) : (unsigned short*)nullptr;
#pragma unroll
    for (int g = 0; g < 4; ++g) {
      float2 mr = mnrs[crow0 + g];
      float n0 = tanh_(fmaf((vc0[g] - mr.x) * mr.y, cw0, cb0));
      float n1 = tanh_(fmaf((vc1[g] - mr.x) * mr.y, cw1, cb1));
      float h0n = fmaf(zf[0][g], n0 - hm[0][g], hm[0][g]);
      float h1n = fmaf(zf[1][g], n1 - hm[1][g], hm[1][g]);
      hm[0][g] = h0n; hm[1][g] = h1n;
      unsigned short hb0 = f2bf(h0n), hb1 = f2bf(h1n);
      h_s[crow0 + g][colr0] = hb0;
      h_s[crow0 + g][colr1] = hb1;
      if (L0) {
        hrow[(size_t)(crow0 + g) * 256 + colr0] = hb0;
        hrow[(size_t)(crow0 + g) * 256 + colr1] = hb1;
      }
    }
    __syncthreads();                                   // B4
  }

#pragma unroll
  for (int g = 0; g < 4; ++g) {
    hstate[(size_t)(b0 + crow0 + g) * 256 + colr0] = hm[0][g];
    hstate[(size_t)(b0 + crow0 + g) * 256 + colr1] = hm[1][g];
  }
}

// ------------------------------- FC head -------------------------------------
__launch_bounds__(256)
__global__ void head_k(const float* __restrict__ h1, const float* __restrict__ fcW,
                       const float* __restrict__ fcb, float* __restrict__ out) {
  __shared__ float hs[16][256];
  const int tid = threadIdx.x, b0 = blockIdx.x * 16;
  for (int i = tid; i < 16 * 64; i += 256) {
    int r = i >> 6, c4 = (i & 63) * 4;
    *reinterpret_cast<float4*>(&hs[r][c4]) =
        *reinterpret_cast<const float4*>(&h1[(size_t)(b0 + r) * 256 + c4]);
  }
  __syncthreads();
  int r = tid >> 4, o = (tid & 15) * 4;
  float a0 = fcb[o], a1 = fcb[o + 1], a2 = fcb[o + 2], a3 = fcb[o + 3];
  for (int k = 0; k < 256; ++k) {
    float h = hs[r][k];
    a0 = fmaf(h, fcW[(size_t)(o + 0) * 256 + k], a0);
    a1 = fmaf(h, fcW[(size_t)(o + 1) * 256 + k], a1);
    a2 = fmaf(h, fcW[(size_t)(o + 2) * 256 + k], a2);
    a3 = fmaf(h, fcW[(size_t)(o + 3) * 256 + k], a3);
  }
  float4 ov = {a0, a1, a2, a3};
  *reinterpret_cast<float4*>(&out[(size_t)(b0 + r) * 64 + o]) = ov;
}

// --------------------------------- host --------------------------------------
extern "C" void kernel_launch(void* const* d_in, const int* in_sizes, int n_in,
                              void* d_out, int out_size, void* d_ws, size_t ws_size,
                              hipStream_t stream) {
  (void)in_sizes; (void)n_in; (void)out_size;
  const float* x    = (const float*)d_in[0];
  const float* Wg0  = (const float*)d_in[1];
  const float* bg0  = (const float*)d_in[2];
  const float* gnw0 = (const float*)d_in[3];
  const float* gnb0 = (const float*)d_in[4];
  const float* Wc0  = (const float*)d_in[5];
  const float* bc0  = (const float*)d_in[6];
  const float* cnw0 = (const float*)d_in[7];
  const float* cnb0 = (const float*)d_in[8];
  const float* Wg1  = (const float*)d_in[9];
  const float* bg1  = (const float*)d_in[10];
  const float* gnw1 = (const float*)d_in[11];
  const float* gnb1 = (const float*)d_in[12];
  const float* Wc1  = (const float*)d_in[13];
  const float* bc1  = (const float*)d_in[14];
  const float* cnw1 = (const float*)d_in[15];
  const float* cnb1 = (const float*)d_in[16];
  const float* fcW  = (const float*)d_in[17];
  const float* fcb  = (const float*)d_in[18];

  float* hst0 = (float*)d_ws;                 // 512*256
  float* hst1 = hst0 + 131072;
  float* b768_0 = hst1 + 131072;
  float* b768_1 = b768_0 + 768;
  unsigned short* g0h = (unsigned short*)(b768_1 + 768);
  unsigned short* c0h = g0h + 131072;
  unsigned short* g1h = c0h + 65536;
  unsigned short* c1h = g1h + 131072;
  unsigned short* wx0 = c1h + 65536;
  unsigned short* wx1 = wx0 + 49152;
  unsigned short* dynbase = wx1 + 196608;

  const size_t fixed_bytes = (size_t)((char*)dynbase - (char*)d_ws);
  int TC = 128;
  while (TC > 8) {
    size_t need = fixed_bytes + (size_t)TC * (262144 + 2 * 786432);
    if (need <= ws_size) break;
    TC >>= 1;
  }
  const int NC = T_ / TC;

  unsigned short* P0c = dynbase;
  unsigned short* P1c = P0c + (size_t)TC * 393216;
  unsigned short* h0c = P1c + (size_t)TC * 393216;

  prep_frag<<<512, 256, 0, stream>>>(Wg0, g0h, 512, 320, 64);
  prep_frag<<<256, 256, 0, stream>>>(Wc0, c0h, 256, 320, 64);
  prep_frag<<<512, 256, 0, stream>>>(Wg1, g1h, 512, 512, 256);
  prep_frag<<<256, 256, 0, stream>>>(Wc1, c1h, 256, 512, 256);
  prep_wx<<<192, 256, 0, stream>>>(Wg0, Wc0, wx0, 64, 320, 320);
  prep_wx<<<768, 256, 0, stream>>>(Wg1, Wc1, wx1, 256, 512, 512);
  bias_cat<<<3, 256, 0, stream>>>(bg0, bc0, b768_0);
  bias_cat<<<3, 256, 0, stream>>>(bg1, bc1, b768_1);

  dim3 pgrid(4 * TC, 6);
  for (int c = 0; c < NC; ++c) {
    precomp<64, true><<<pgrid, 256, 0, stream>>>(x, wx0, b768_0, P0c, TC, c * TC);
    if (c == 0)
      gru_layer<true, true><<<32, 512, 0, stream>>>(g0h, c0h, P0c,
          gnw0, gnb0, cnw0, cnb0, hst0, h0c, TC);
    else
      gru_layer<false, true><<<32, 512, 0, stream>>>(g0h, c0h, P0c,
          gnw0, gnb0, cnw0, cnb0, hst0, h0c, TC);
    precomp<256, false><<<pgrid, 256, 0, stream>>>(h0c, wx1, b768_1, P1c, TC, 0);
    if (c == 0)
      gru_layer<true, false><<<32, 512, 0, stream>>>(g1h, c1h, P1c,
          gnw1, gnb1, cnw1, cnb1, hst1, (unsigned short*)nullptr, TC);
    else
      gru_layer<false, false><<<32, 512, 0, stream>>>(g1h, c1h, P1c,
          gnw1, gnb1, cnw1, cnb1, hst1, (unsigned short*)nullptr, TC);
  }
  head_k<<<32, 256, 0, stream>>>(hst1, fcW, fcb, (float*)d_out);
}